// Round 7
// baseline (98.871 us; speedup 1.0000x reference)
//
#include <hip/hip_runtime.h>
#include <math.h>

// Problem constants
#define T_STEPS 50
#define NS      2048
#define IND     16
#define HID     128
#define GATES   512
#define RR      8
#define KN      32
#define EPSV    1e-10f

// LSTM MFMA tiling: 512 blocks x 4 rows x 8 waves -> 2 independent blocks/CU
// (two barrier groups per CU; fills the round-6 phase-lock bubbles).
#define LROWS   4
#define APAD    168     // f16 row stride: 336B -> 2-way bank aliasing only (free)
#define LTH     512     // 8 waves; wave w owns gate cols [16w,16w+16) per group

typedef _Float16 f16x8 __attribute__((ext_vector_type(8)));
typedef _Float16 f16x4 __attribute__((ext_vector_type(4)));
typedef float    f32x4 __attribute__((ext_vector_type(4)));

// Fast activations: raw v_rcp_f32 (1 ULP) instead of precise-div sequence.
__device__ __forceinline__ float rcp_(float x)  { return __builtin_amdgcn_rcpf(x); }
__device__ __forceinline__ float sigm(float x)  { return rcp_(1.0f + __expf(-x)); }
__device__ __forceinline__ float tanhf_(float x){ return 1.0f - 2.0f * rcp_(1.0f + __expf(2.0f * x)); }

// ---------------------------------------------------------------------------
// LSTM via MFMA f16. 4 real rows at M-rows {0,4,8,12} of the 16-row tile:
// C-reg r=0 of every lane is a real cell (1 cell/lane, no cross-lane ops).
// K layout per sA row: [x(cols 0..15) | h(cols 16..143) | pad].
// x-part via 16x16x16 MFMA (f16x4 frags), h-part via 4x 16x16x32.
// Weights register-resident (keep-alive asm); x LDS-staged; double-buffered
// sA; one barrier per step. __launch_bounds__(512,4) targets <=128 regs so
// 2 blocks (16 waves) fit per CU.
// ---------------------------------------------------------------------------
__global__ __launch_bounds__(LTH, 4) void lstm_mfma_kernel(
    const float* __restrict__ x,     // (T, NS, IND)
    const float* __restrict__ W_ih,  // (GATES, IND)
    const float* __restrict__ W_hh,  // (GATES, HID)
    const float* __restrict__ b_ih,  // (GATES)
    const float* __restrict__ b_hh,  // (GATES)
    float* __restrict__ se)          // (NS, HID) out
{
    __shared__ __align__(16) _Float16 sA[2][16][APAD];           // 10.75 KB
    __shared__ __align__(16) _Float16 sX[T_STEPS][LROWS * IND];  // 6.4 KB

    const int tid    = threadIdx.x;
    const int w      = tid >> 6;       // wave 0..7
    const int l      = tid & 63;
    const int lane16 = l & 15;
    const int lgrp   = l >> 4;         // 0..3 (MFMA fragment k-group)
    const int n0     = blockIdx.x * LROWS;

    // ---- prologue: W -> f16 fragments in registers (static all 50 steps)
    // gate col gi = 128*gg + 16*w + lane16
    // Bx[gg]:     k = lgrp*4 + j        (x part, K=16, 16x16x16 frag)
    // Bh[gg][kf]: k = kf*32 + lgrp*8 + j (h part, K=128, 16x16x32 frags)
    f16x8 Bh[4][4];
    f16x4 Bx[4];
    float bias[4];
#pragma unroll
    for (int gg = 0; gg < 4; ++gg) {
        const int gi = 128 * gg + 16 * w + lane16;
        bias[gg] = b_ih[gi] + b_hh[gi];
        f16x4 vx;
#pragma unroll
        for (int j = 0; j < 4; ++j)
            vx[j] = (_Float16)W_ih[gi * IND + lgrp * 4 + j];
        Bx[gg] = vx;
#pragma unroll
        for (int kf = 0; kf < 4; ++kf) {
            f16x8 v;
            const float* p = W_hh + gi * HID + kf * 32 + lgrp * 8;
#pragma unroll
            for (int j = 0; j < 8; ++j) v[j] = (_Float16)p[j];
            Bh[gg][kf] = v;
        }
    }
    // Opaque to the optimizer: cannot rematerialize -> stays resident.
#pragma unroll
    for (int gg = 0; gg < 4; ++gg) {
        asm volatile("" : "+v"(Bx[gg]));
#pragma unroll
        for (int kf = 0; kf < 4; ++kf)
            asm volatile("" : "+v"(Bh[gg][kf]));
    }

    // zero both sA buffers (dummy M-rows + K-pad stay zero forever)
    for (int i = tid; i < 2 * 16 * APAD; i += LTH)
        (&sA[0][0][0])[i] = (_Float16)0.0f;

    // stage ALL x for this block's 4 rows, f16 (coalesced, once)
    for (int i = tid; i < T_STEPS * LROWS * IND; i += LTH) {
        const int t = i >> 6, e = i & 63;
        sX[t][e] = (_Float16)x[((size_t)t * NS + n0) * IND + e];
    }
    __syncthreads();
    // x_0: real row r -> M-row 4r, cols 0..15
    if (tid < LROWS * IND) sA[0][4 * (tid >> 4)][tid & 15] = sX[0][tid];
    __syncthreads();

    // lane owns ONE cell: (row lgrp, col 16w+lane16) = C-reg r=0 of M-row 4*lgrp
    float c = 0.f, h = 0.f;

    for (int step = 0; step < T_STEPS; ++step) {
        const int cur = step & 1, nxt = cur ^ 1;

        // x-part A fragment (K=16): row = lane16, k = lgrp*4..+4
        f16x4 Ax = *(const f16x4*)&sA[cur][lane16][lgrp * 4];

        _Float16 xv = (_Float16)0.0f;
        if (step + 1 < T_STEPS && tid < LROWS * IND) xv = sX[step + 1][tid];

        f32x4 az0 = {bias[0], bias[0], bias[0], bias[0]};
        f32x4 az1 = {bias[1], bias[1], bias[1], bias[1]};
        f32x4 az2 = {bias[2], bias[2], bias[2], bias[2]};
        f32x4 az3 = {bias[3], bias[3], bias[3], bias[3]};
        az0 = __builtin_amdgcn_mfma_f32_16x16x16f16(Ax, Bx[0], az0, 0, 0, 0);
        az1 = __builtin_amdgcn_mfma_f32_16x16x16f16(Ax, Bx[1], az1, 0, 0, 0);
        az2 = __builtin_amdgcn_mfma_f32_16x16x16f16(Ax, Bx[2], az2, 0, 0, 0);
        az3 = __builtin_amdgcn_mfma_f32_16x16x16f16(Ax, Bx[3], az3, 0, 0, 0);
#pragma unroll
        for (int kf = 0; kf < 4; ++kf) {
            // h-part A fragment loaded per-kf (keeps register pressure low)
            f16x8 Ah = *(const f16x8*)&sA[cur][lane16][16 + kf * 32 + lgrp * 8];
            az0 = __builtin_amdgcn_mfma_f32_16x16x32_f16(Ah, Bh[0][kf], az0, 0, 0, 0);
            az1 = __builtin_amdgcn_mfma_f32_16x16x32_f16(Ah, Bh[1][kf], az1, 0, 0, 0);
            az2 = __builtin_amdgcn_mfma_f32_16x16x32_f16(Ah, Bh[2][kf], az2, 0, 0, 0);
            az3 = __builtin_amdgcn_mfma_f32_16x16x32_f16(Ah, Bh[3][kf], az3, 0, 0, 0);
        }

        // cell update on C-reg 0 only (the real row); no cross-lane ops
        c = sigm(az1[0]) * c + sigm(az0[0]) * tanhf_(az2[0]);
        h = sigm(az3[0]) * tanhf_(c);

        // write x_{t+1}, h_{t+1} into the other buffer; one barrier per step
        if (step + 1 < T_STEPS) {
            if (tid < LROWS * IND) sA[nxt][4 * (tid >> 4)][tid & 15] = xv;
            sA[nxt][4 * lgrp][16 + 16 * w + lane16] = (_Float16)h;
        }
        __syncthreads();
    }

    se[(n0 + lgrp) * HID + 16 * w + lane16] = h;
}

// ---------------------------------------------------------------------------
// Kernel 2: FUSED neighbor attention + relation combine. One block per stock
// n (512 thr, 8 waves); wave r handles relation r wave-locally (no barrier
// in the heavy phase), then one block barrier, block softmax over R, and
// wave 0 does the final projection. Kills the combine launch and the 16 MB
// rel_rep/rscore L2 round-trip.
// ---------------------------------------------------------------------------
__global__ __launch_bounds__(512) void attn_fused_kernel(
    const float* __restrict__ se,        // (NS, HID)
    const int*   __restrict__ neighbors, // (RR, NS, KN)
    const float* __restrict__ rel_num,   // (RR, NS)
    const float* __restrict__ w_att,     // (2H + R)
    const float* __restrict__ b_att,     // (1)
    const float* __restrict__ w_rel,     // (H + R)
    const float* __restrict__ b_rel,     // (1)
    const float* __restrict__ w_fc1,     // (HID)
    const float* __restrict__ b_fc1,     // (1)
    float* __restrict__ out)             // (NS)
{
    __shared__ _Float16 snb[RR][KN][HID + 8];   // 69.6 KB
    __shared__ float    srel[RR][HID];          // 4 KB
    __shared__ float    srsc[RR];
    __shared__ int      sidx[RR][KN];

    const int r    = threadIdx.x >> 6;   // wave = relation 0..7
    const int lane = threadIdx.x & 63;
    const int n    = blockIdx.x;
    const size_t pair = (size_t)r * NS + n;

    if (lane < KN) sidx[r][lane] = neighbors[pair * KN + lane];
    // wave-local write->read on sidx/snb: ordered by lgkmcnt, no barrier.

    const float4* se4 = (const float4*)se;
#pragma unroll
    for (int m = 0; m < (KN * HID / 4) / 64; ++m) {   // 16 iters
        int flat = m * 64 + lane;
        int row  = flat >> 5;
        int c4   = flat & 31;
        int idx  = sidx[r][row];
        float4 v = make_float4(0.f, 0.f, 0.f, 0.f);
        if (idx != 0) v = se4[(size_t)(idx - 1) * (HID / 4) + c4];
        f16x4 hv = { (_Float16)v.x, (_Float16)v.y, (_Float16)v.z, (_Float16)v.w };
        *((f16x4*)&snb[r][row][c4 * 4]) = hv;
    }

    // self-dot (redundant across waves; cheap)
    float p2 = se[n * HID + lane] * w_att[HID + lane]
             + se[n * HID + 64 + lane] * w_att[HID + 64 + lane];
#pragma unroll
    for (int d = 32; d > 0; d >>= 1) p2 += __shfl_xor(p2, d);

    // neighbor scores: lane (k, half) computes half-dot; combine halves
    const int k    = lane & 31;
    const int half = lane >> 5;
    float ps = 0.f;
#pragma unroll
    for (int h4 = 0; h4 < 16; ++h4) {
        f16x4  v  = *(const f16x4*)&snb[r][k][half * 64 + h4 * 4];
        float4 wv = *(const float4*)&w_att[half * 64 + h4 * 4];
        ps += (float)v[0] * wv.x + (float)v[1] * wv.y
            + (float)v[2] * wv.z + (float)v[3] * wv.w;
    }
    ps += __shfl_down(ps, 32);   // lanes 0..31 hold full dots

    float s = ps + p2 + w_att[2 * HID + r] + b_att[0];
    float mx = s;
#pragma unroll
    for (int d = 16; d > 0; d >>= 1) mx = fmaxf(mx, __shfl_xor(mx, d, 32));
    float e  = __expf(s - mx);
    float sm = e;
#pragma unroll
    for (int d = 16; d > 0; d >>= 1) sm += __shfl_xor(sm, d, 32);
    float att = e / sm;

    // rel_rep: lane handles h = lane and lane+64
    const float inv = 1.0f / (rel_num[pair] + EPSV);
    float a0 = 0.f, a1 = 0.f;
#pragma unroll
    for (int kk = 0; kk < KN; ++kk) {
        float av = __shfl(att, kk);
        a0 += av * (float)snb[r][kk][lane];
        a1 += av * (float)snb[r][kk][64 + lane];
    }
    a0 *= inv;
    a1 *= inv;
    srel[r][lane]      = a0;
    srel[r][64 + lane] = a1;

    float pr = a0 * w_rel[lane] + a1 * w_rel[64 + lane];
#pragma unroll
    for (int d = 32; d > 0; d >>= 1) pr += __shfl_xor(pr, d);
    if (lane == 0) srsc[r] = pr + w_rel[HID + r] + b_rel[0];

    __syncthreads();   // the only block-wide barrier

    // combine: wave 0 does softmax over R + weighted mean + residual + fc1
    if (r == 0) {
        float rs[RR];
        float rmx = -1e30f;
#pragma unroll
        for (int q = 0; q < RR; ++q) {
            rs[q] = srsc[q];
            rmx = fmaxf(rmx, rs[q]);
        }
        float rsm = 0.f;
#pragma unroll
        for (int q = 0; q < RR; ++q) {
            rs[q] = __expf(rs[q] - rmx);
            rsm += rs[q];
        }
        const float invs = rcp_(rsm * (float)RR);

        float u0 = 0.f, u1 = 0.f;
#pragma unroll
        for (int q = 0; q < RR; ++q) {
            u0 += rs[q] * srel[q][lane];
            u1 += rs[q] * srel[q][64 + lane];
        }
        u0 = u0 * invs + se[n * HID + lane];
        u1 = u1 * invs + se[n * HID + 64 + lane];

        float p = u0 * w_fc1[lane] + u1 * w_fc1[64 + lane];
#pragma unroll
        for (int d = 32; d > 0; d >>= 1) p += __shfl_xor(p, d);
        if (lane == 0) out[n] = p + b_fc1[0];
    }
}

// ---------------------------------------------------------------------------
extern "C" void kernel_launch(void* const* d_in, const int* in_sizes, int n_in,
                              void* d_out, int out_size, void* d_ws, size_t ws_size,
                              hipStream_t stream) {
    const float* x      = (const float*)d_in[0];
    const int*   nbrs   = (const int*)  d_in[1];
    const float* relnum = (const float*)d_in[2];
    const float* W_ih   = (const float*)d_in[3];
    const float* W_hh   = (const float*)d_in[4];
    const float* b_ih   = (const float*)d_in[5];
    const float* b_hh   = (const float*)d_in[6];
    const float* w_att  = (const float*)d_in[7];
    const float* b_att  = (const float*)d_in[8];
    const float* w_rel  = (const float*)d_in[9];
    const float* b_rel  = (const float*)d_in[10];
    const float* w_fc1  = (const float*)d_in[11];
    const float* b_fc1  = (const float*)d_in[12];
    float* out = (float*)d_out;

    float* se = (float*)d_ws;   // (NS, HID) fp32

    hipLaunchKernelGGL(lstm_mfma_kernel, dim3(NS / LROWS), dim3(LTH), 0, stream,
                       x, W_ih, W_hh, b_ih, b_hh, se);
    hipLaunchKernelGGL(attn_fused_kernel, dim3(NS), dim3(512), 0, stream,
                       se, nbrs, relnum, w_att, b_att, w_rel, b_rel,
                       w_fc1, b_fc1, out);
}